// Round 4
// baseline (162.158 us; speedup 1.0000x reference)
//
#include <hip/hip_runtime.h>

#define VOCAB 100000
#define DIM 128
#define BATCH 65536
#define N_NEG 10

// 8 lanes/element, 8 elements/wave, 4 waves/block => 32 elements/block
#define BLOCKS (BATCH / 32)   // 2048

__device__ __forceinline__ float softplus_f(float x) {
    // log(1+exp(x)), stable
    return fmaxf(x, 0.0f) + log1pf(__expf(-fabsf(x)));
}

__device__ __forceinline__ float dot4(float4 a, float4 b) {
    return a.x * b.x + a.y * b.y + a.z * b.z + a.w * b.w;
}

__global__ void zero_out_kernel(float* out) { out[0] = 0.0f; }

// launch_bounds(256,4): cap VGPR at 128 -> 4 waves/SIMD while allowing
// ~22 outstanding float4 loads per wave (chunk-major + hoisted next chunk).
__global__ __launch_bounds__(256, 4) void skipgram_loss_kernel(
    const int* __restrict__ pos_u,
    const int* __restrict__ pos_v,
    const int* __restrict__ neg_v,
    const float4* __restrict__ u_weight,   // VOCAB x 32 float4
    const float4* __restrict__ v_weight,   // VOCAB x 32 float4
    float* __restrict__ out)
{
    const int tid  = threadIdx.x;
    const int lane = tid & 63;
    const int wave = tid >> 6;      // 0..3
    const int sub  = lane & 7;      // 0..7 within the 8-lane group
    const int grp  = lane >> 3;     // 0..7: group within wave

    const int b = (blockIdx.x * 4 + wave) * 8 + grp;   // one batch element per group

    const int iu = pos_u[b];
    const int iv = pos_v[b];
    int idx[N_NEG];
    #pragma unroll
    for (int n = 0; n < N_NEG; ++n) idx[n] = neg_v[b * N_NEG + n];

    const float4* __restrict__ urow = u_weight + iu * 32 + sub;
    const float4* rows[N_NEG + 1];
    rows[0] = v_weight + iv * 32 + sub;
    #pragma unroll
    for (int n = 0; n < N_NEG; ++n) rows[n + 1] = v_weight + idx[n] * 32 + sub;

    // preload the full u row (4 chunks, 16 VGPRs)
    float4 u[4];
    #pragma unroll
    for (int c = 0; c < 4; ++c) u[c] = urow[c * 8];

    float acc[N_NEG + 1];
    #pragma unroll
    for (int j = 0; j <= N_NEG; ++j) acc[j] = 0.0f;

    // chunk-major: per chunk, 11 independent gathers issued back-to-back
    #pragma unroll
    for (int c = 0; c < 4; ++c) {
        float4 w[N_NEG + 1];
        #pragma unroll
        for (int j = 0; j <= N_NEG; ++j) w[j] = rows[j][c * 8];
        #pragma unroll
        for (int j = 0; j <= N_NEG; ++j) acc[j] += dot4(u[c], w[j]);
    }

    // reduce the 11 partial dots across the 8-lane group (3 levels)
    #pragma unroll
    for (int m = 1; m < 8; m <<= 1) {
        #pragma unroll
        for (int j = 0; j <= N_NEG; ++j) acc[j] += __shfl_xor(acc[j], m, 64);
    }

    float s = fminf(fmaxf(acc[0], -10.0f), 10.0f);
    float loss = softplus_f(-s);              // -log_sigmoid(s)
    #pragma unroll
    for (int n = 0; n < N_NEG; ++n)
        loss -= softplus_f(acc[n + 1]);       // + log_sigmoid(-d) == -softplus(d)

    // Each 8-lane group holds its loss (uniform within the group). Butterfly
    // over masks 8,16,32 pairs lanes of DIFFERENT groups -> every lane ends
    // with the sum of the 8 distinct group losses, each counted exactly once.
    #pragma unroll
    for (int m = 8; m < 64; m <<= 1) loss += __shfl_xor(loss, m, 64);

    __shared__ float smem[4];
    if (lane == 0) smem[wave] = loss;
    __syncthreads();
    if (tid == 0) {
        atomicAdd(out, (smem[0] + smem[1] + smem[2] + smem[3]) * (1.0f / (float)BATCH));
    }
}

extern "C" void kernel_launch(void* const* d_in, const int* in_sizes, int n_in,
                              void* d_out, int out_size, void* d_ws, size_t ws_size,
                              hipStream_t stream) {
    const int*    pos_u    = (const int*)d_in[0];
    const int*    pos_v    = (const int*)d_in[1];
    const int*    neg_v    = (const int*)d_in[2];
    const float4* u_weight = (const float4*)d_in[3];
    const float4* v_weight = (const float4*)d_in[4];
    float* out = (float*)d_out;

    zero_out_kernel<<<1, 1, 0, stream>>>(out);
    skipgram_loss_kernel<<<BLOCKS, 256, 0, stream>>>(
        pos_u, pos_v, neg_v, u_weight, v_weight, out);
}